// Round 1
// baseline (2898.447 us; speedup 1.0000x reference)
//
#include <hip/hip_runtime.h>
#include <stdint.h>

#define B_  64
#define S_  2048
#define U_  1024
#define V_  50257
#define L_  8

typedef __attribute__((ext_vector_type(4))) float  f32x4;
typedef __attribute__((ext_vector_type(8))) short  bf16x8;
typedef __attribute__((ext_vector_type(4))) unsigned short us4;

__device__ inline unsigned short f2bf(float f){
  union { float f; unsigned u; } x; x.f = f;
  unsigned r = (x.u + 0x7FFFu + ((x.u >> 16) & 1u)) >> 16;  // RNE
  return (unsigned short)r;
}
__device__ inline float fast_tanh(float x){
  float e = __expf(2.0f * x);
  return (e - 1.0f) * __builtin_amdgcn_rcpf(e + 1.0f);
}
__device__ inline void gload_lds16(const void* g, void* l){
  __builtin_amdgcn_global_load_lds(
      (const __attribute__((address_space(1))) unsigned int*)g,
      (__attribute__((address_space(3))) unsigned int*)l, 16, 0, 0);
}

// ---------------- K1a: W1 (u,v) fp32 -> W1T (v,u) bf16 ----------------
__global__ void k1a_w1t(const float* __restrict__ W1, unsigned short* __restrict__ W1T){
  __shared__ float tile[64][65];
  int bu = blockIdx.x & 15, bv = blockIdx.x >> 4;
  int u0 = bu * 64, v0 = bv * 64;
  int t = threadIdx.x;
  int r = t >> 6, c = t & 63;
  #pragma unroll 4
  for (int it = 0; it < 16; ++it){
    int rr = it * 4 + r;
    tile[rr][c] = W1[(long)(u0 + rr) * 1024 + v0 + c];
  }
  __syncthreads();
  #pragma unroll 4
  for (int it = 0; it < 16; ++it){
    int vr = it * 4 + r;
    W1T[(long)(v0 + vr) * 1024 + u0 + c] = f2bf(tile[c][vr]);
  }
}

// ---------------- K1b: qbias = query_h @ W2 + b2 + b1 ----------------
__global__ void k1b_qbias(const float* __restrict__ qh, const float* __restrict__ W2,
                          const float* __restrict__ b1, const float* __restrict__ b2,
                          float* __restrict__ qbias){
  int b = blockIdx.x >> 2;
  int v = (blockIdx.x & 3) * 256 + threadIdx.x;
  const float* qr = qh + b * 1024;
  float a = 0.f;
  for (int j = 0; j < 256; ++j){
    f32x4 qv = *(const f32x4*)(qr + j * 4);
    a += qv[0] * W2[(long)(j*4+0)*1024 + v] + qv[1] * W2[(long)(j*4+1)*1024 + v]
       + qv[2] * W2[(long)(j*4+2)*1024 + v] + qv[3] * W2[(long)(j*4+3)*1024 + v];
  }
  qbias[b * 1024 + v] = a + b1[v] + b2[v];
}

// ---------------- K2: fused  score = tanh(enc@W1 + qbias) . attn_V ----------------
// BM=64 rows/block, N=1024 fully in registers (8 waves, wave tile 64x128).
// A: fp32->bf16 reg-staged panels [64][128+8pad]. B: W1T bf16 via global_load_lds,
// chunk-XOR swizzle (c ^= v&7) for conflict-free ds_read_b128.
#define K2T 512
__global__ __launch_bounds__(K2T, 2) void k2_feat_score(
    const float* __restrict__ enc, const unsigned short* __restrict__ W1T,
    const float* __restrict__ qbias, const float* __restrict__ attnV,
    float* __restrict__ score){
  __shared__ __attribute__((aligned(16))) unsigned short Bs[1024 * 64]; // [v][64k] 128KB
  __shared__ __attribute__((aligned(16))) unsigned short As[64 * 136];  // [m][128k+8] 17KB
  __shared__ float qbL[1024], vwL[1024], scoreL[64];

  const int tid  = threadIdx.x;
  const int lane = tid & 63;
  const int w    = tid >> 6;            // wave 0..7
  const int blk  = blockIdx.x;          // 0..2047
  const long row0 = (long)blk * 64;
  const int b = blk >> 5;               // 64 | 2048 -> one batch per block

  for (int i = tid; i < 1024; i += K2T){ qbL[i] = qbias[b*1024 + i]; vwL[i] = attnV[i]; }
  if (tid < 64) scoreL[tid] = 0.0f;

  f32x4 acc[4][8];
  #pragma unroll
  for (int mi = 0; mi < 4; ++mi)
    #pragma unroll
    for (int ni = 0; ni < 8; ++ni) acc[mi][ni] = (f32x4){0.f,0.f,0.f,0.f};

  // precomputed B-stage global element offsets (v*1024 + swizzled-chunk*8)
  int goff[16];
  #pragma unroll
  for (int it = 0; it < 16; ++it){
    int d = it * 512 + tid;
    int v = d >> 3, c = d & 7;
    goff[it] = v * 1024 + (c ^ (v & 7)) * 8;
  }

  for (int p = 0; p < 8; ++p){
    __syncthreads();                               // panel + B buffers reusable
    { // stage A panel p: 64 x 128 fp32 -> bf16 (padded rows)
      const float* src = enc + row0 * 1024 + p * 128;
      #pragma unroll
      for (int it = 0; it < 4; ++it){
        int idx = it * 512 + tid;                  // 0..2047
        int r = idx >> 5, c4 = idx & 31;
        f32x4 v4 = *(const f32x4*)(src + (long)r * 1024 + c4 * 4);
        us4 sv;
        sv[0] = f2bf(v4[0]); sv[1] = f2bf(v4[1]); sv[2] = f2bf(v4[2]); sv[3] = f2bf(v4[3]);
        *(us4*)&As[r * 136 + c4 * 4] = sv;
      }
    }
    #pragma unroll
    for (int s2 = 0; s2 < 2; ++s2){
      __syncthreads();                             // prev compute done -> Bs writable
      const int kk = p * 128 + s2 * 64;
      #pragma unroll
      for (int it = 0; it < 16; ++it){             // stage B tile [1024][64] bf16
        int dbase = it * 512 + w * 64;             // wave-uniform LDS slot base
        gload_lds16(W1T + goff[it] + kk, &Bs[dbase * 8]);
      }
      __syncthreads();                             // vmcnt drained by compiler
      #pragma unroll
      for (int k0 = 0; k0 < 2; ++k0){
        bf16x8 af[4];
        #pragma unroll
        for (int mi = 0; mi < 4; ++mi){
          int r = mi * 16 + (lane & 15);
          int kloc = s2 * 64 + k0 * 32 + (lane >> 4) * 8;
          af[mi] = *(const bf16x8*)&As[r * 136 + kloc];
        }
        #pragma unroll
        for (int ni = 0; ni < 8; ++ni){
          int v = w * 128 + ni * 16 + (lane & 15);
          int c = k0 * 4 + (lane >> 4);
          bf16x8 bf = *(const bf16x8*)&Bs[v * 64 + (c ^ (v & 7)) * 8];
          #pragma unroll
          for (int mi = 0; mi < 4; ++mi)
            acc[mi][ni] = __builtin_amdgcn_mfma_f32_16x16x32_bf16(af[mi], bf, acc[mi][ni], 0, 0, 0);
        }
      }
    }
  }
  // epilogue: feat = acc + qb; score_row += tanh(feat)*Vw, reduce over cols
  float qv[8], vv[8];
  #pragma unroll
  for (int ni = 0; ni < 8; ++ni){
    int col = w * 128 + ni * 16 + (lane & 15);
    qv[ni] = qbL[col]; vv[ni] = vwL[col];
  }
  #pragma unroll
  for (int mi = 0; mi < 4; ++mi){
    #pragma unroll
    for (int r = 0; r < 4; ++r){
      float t = 0.f;
      #pragma unroll
      for (int ni = 0; ni < 8; ++ni)
        t += fast_tanh(acc[mi][ni][r] + qv[ni]) * vv[ni];
      #pragma unroll
      for (int off = 1; off < 16; off <<= 1) t += __shfl_xor(t, off, 16);
      if ((lane & 15) == 0)
        atomicAdd(&scoreL[mi * 16 + (lane >> 4) * 4 + r], t);
    }
  }
  __syncthreads();
  if (tid < 64) score[row0 + tid] = scoreL[tid];
}

// ---------------- K3: softmax over S per batch (attn_bV cancels) ----------------
__global__ void k3_softmax_s(const float* __restrict__ score, float* __restrict__ attnw){
  __shared__ float red[256];
  int b = blockIdx.x, t = threadIdx.x;
  const float* sc = score + b * 2048;
  float m = -1e30f;
  for (int i = t; i < 2048; i += 256) m = fmaxf(m, sc[i]);
  red[t] = m; __syncthreads();
  for (int s = 128; s > 0; s >>= 1){ if (t < s) red[t] = fmaxf(red[t], red[t+s]); __syncthreads(); }
  float M = red[0]; __syncthreads();
  float p = 0.f;
  for (int i = t; i < 2048; i += 256) p += __expf(sc[i] - M);
  red[t] = p; __syncthreads();
  for (int s = 128; s > 0; s >>= 1){ if (t < s) red[t] += red[t+s]; __syncthreads(); }
  float inv = 1.0f / red[0];
  for (int i = t; i < 2048; i += 256) attnw[b * 2048 + i] = __expf(sc[i] - M) * inv;
}

// ---------------- K4: ctx[b,u] = sum_s attn_w[b,s] * enc[b,s,u] (BW-bound) ----------------
__global__ void k4_ctx(const float* __restrict__ enc, const float* __restrict__ attnw,
                       float* __restrict__ ctx){
  __shared__ float wL[2048];
  __shared__ f32x4 red[8][32];
  int b = blockIdx.x >> 3, uc = blockIdx.x & 7;
  int t = threadIdx.x;
  for (int i = t; i < 2048; i += 256) wL[i] = attnw[b * 2048 + i];
  __syncthreads();
  int g = t >> 5, l32 = t & 31;
  const float* base = enc + (long)b * 2048 * 1024 + uc * 128 + l32 * 4;
  f32x4 a = (f32x4){0.f,0.f,0.f,0.f};
  for (int s = g; s < 2048; s += 8){
    f32x4 e = *(const f32x4*)(base + (long)s * 1024);
    a += e * wL[s];
  }
  red[g][l32] = a; __syncthreads();
  if (g == 0){
    f32x4 r = red[0][l32];
    #pragma unroll
    for (int i = 1; i < 8; ++i) r += red[i][l32];
    *(f32x4*)(ctx + b * 1024 + uc * 128 + l32 * 4) = r;
  }
}

// ---------------- K5a: z-partials for gates i,g,o (f is dead).  split-K=8 ----------------
__global__ void k5a_gemm(const float* __restrict__ x, const float* __restrict__ ctx,
                         const float* __restrict__ W, float* __restrict__ zpart){
  __shared__ float inpL[64 * 256];          // this K-chunk of inp, 64KB
  int blk = blockIdx.x;
  int nc = blk % 48, ks = blk / 48;
  int t = threadIdx.x;
  int gc = (nc < 16) ? nc * 64 : (nc < 32 ? 2048 + (nc - 16) * 64 : 3072 + (nc - 32) * 64);
  const float* ib = (ks < 4) ? x : ctx;
  int koff = (ks & 3) * 256;
  #pragma unroll 4
  for (int it = 0; it < 16; ++it){
    int idx = it * 256 + t;                 // 0..4095: r=idx>>6, c4=idx&63
    int r = idx >> 6, c4 = idx & 63;
    *(f32x4*)&inpL[r * 256 + c4 * 4] = *(const f32x4*)(ib + (long)r * 1024 + koff + c4 * 4);
  }
  __syncthreads();
  int b4 = (t & 15) * 4, n4 = (t >> 4) * 4;
  f32x4 a0 = (f32x4){0,0,0,0}, a1 = a0, a2 = a0, a3 = a0;
  const float* Wb = W + (long)(ks * 256) * 4096 + gc + n4;
  #pragma unroll 2
  for (int j = 0; j < 64; ++j){
    f32x4 w0 = *(const f32x4*)(Wb + (long)(j*4+0) * 4096);
    f32x4 w1 = *(const f32x4*)(Wb + (long)(j*4+1) * 4096);
    f32x4 w2 = *(const f32x4*)(Wb + (long)(j*4+2) * 4096);
    f32x4 w3 = *(const f32x4*)(Wb + (long)(j*4+3) * 4096);
    f32x4 x0 = *(const f32x4*)&inpL[(b4+0) * 256 + j * 4];
    f32x4 x1 = *(const f32x4*)&inpL[(b4+1) * 256 + j * 4];
    f32x4 x2 = *(const f32x4*)&inpL[(b4+2) * 256 + j * 4];
    f32x4 x3 = *(const f32x4*)&inpL[(b4+3) * 256 + j * 4];
    a0 += w0*x0[0]; a0 += w1*x0[1]; a0 += w2*x0[2]; a0 += w3*x0[3];
    a1 += w0*x1[0]; a1 += w1*x1[1]; a1 += w2*x1[2]; a1 += w3*x1[3];
    a2 += w0*x2[0]; a2 += w1*x2[1]; a2 += w2*x2[2]; a2 += w3*x2[3];
    a3 += w0*x3[0]; a3 += w1*x3[1]; a3 += w2*x3[2]; a3 += w3*x3[3];
  }
  float* zp = zpart + (long)ks * 64 * 3072 + nc * 64 + n4;
  *(f32x4*)(zp + (long)(b4+0) * 3072) = a0;
  *(f32x4*)(zp + (long)(b4+1) * 3072) = a1;
  *(f32x4*)(zp + (long)(b4+2) * 3072) = a2;
  *(f32x4*)(zp + (long)(b4+3) * 3072) = a3;
}

// ---------------- K5b: reduce split-K, gates, residual, write hs/cs/x ----------------
__global__ void k5b_gates(const float* __restrict__ zpart, const float* __restrict__ lb,
                          const float* __restrict__ xin, float* __restrict__ xout,
                          float* __restrict__ hs, float* __restrict__ cs, int resid){
  int b = blockIdx.x, t = threadIdx.x;
  int n4 = t * 4;
  f32x4 zi = (f32x4){0,0,0,0}, zg = zi, zo = zi;
  #pragma unroll
  for (int ks = 0; ks < 8; ++ks){
    const float* zp = zpart + (long)ks * 64 * 3072 + b * 3072;
    zi += *(const f32x4*)(zp + n4);
    zg += *(const f32x4*)(zp + 1024 + n4);
    zo += *(const f32x4*)(zp + 2048 + n4);
  }
  zi += *(const f32x4*)(lb + n4);
  zg += *(const f32x4*)(lb + 2048 + n4);
  zo += *(const f32x4*)(lb + 3072 + n4);
  f32x4 c, h;
  #pragma unroll
  for (int j = 0; j < 4; ++j){
    float cv = (1.f / (1.f + __expf(-zi[j]))) * tanhf(zg[j]);
    float hv = (1.f / (1.f + __expf(-zo[j]))) * tanhf(cv);
    c[j] = cv; h[j] = hv;
  }
  f32x4 xn = h;
  if (resid) xn += *(const f32x4*)(xin + b * 1024 + n4);
  *(f32x4*)(hs + b * 1024 + n4) = h;
  *(f32x4*)(cs + b * 1024 + n4) = c;
  *(f32x4*)(xout + b * 1024 + n4) = xn;
}

// ---------------- K6: logits = x @ dense_W + db ----------------
__global__ void k6_dense(const float* __restrict__ x, const float* __restrict__ dW,
                         const float* __restrict__ db, float* __restrict__ logits){
  int nc = blockIdx.x, t = threadIdx.x;
  int b4 = (t & 15) * 4, nl = (t >> 4) * 4;
  int col = nc * 64 + nl;
  int c0 = min(col + 0, V_ - 1), c1 = min(col + 1, V_ - 1);
  int c2 = min(col + 2, V_ - 1), c3 = min(col + 3, V_ - 1);
  f32x4 a[4];
  #pragma unroll
  for (int bi = 0; bi < 4; ++bi) a[bi] = (f32x4){0,0,0,0};
  for (int j = 0; j < 256; ++j){
    f32x4 xv0 = *(const f32x4*)(x + (long)(b4+0) * 1024 + j * 4);
    f32x4 xv1 = *(const f32x4*)(x + (long)(b4+1) * 1024 + j * 4);
    f32x4 xv2 = *(const f32x4*)(x + (long)(b4+2) * 1024 + j * 4);
    f32x4 xv3 = *(const f32x4*)(x + (long)(b4+3) * 1024 + j * 4);
    #pragma unroll
    for (int ki = 0; ki < 4; ++ki){
      const float* wr = dW + (long)(j * 4 + ki) * V_;
      f32x4 wv = { wr[c0], wr[c1], wr[c2], wr[c3] };
      a[0] += wv * xv0[ki]; a[1] += wv * xv1[ki];
      a[2] += wv * xv2[ki]; a[3] += wv * xv3[ki];
    }
  }
  f32x4 bias = { db[c0], db[c1], db[c2], db[c3] };
  #pragma unroll
  for (int bi = 0; bi < 4; ++bi){
    f32x4 r = a[bi] + bias;
    #pragma unroll
    for (int j = 0; j < 4; ++j)
      if (col + j < V_) logits[(long)(b4 + bi) * V_ + col + j] = r[j];
  }
}

// ---------------- K7: softmax over V ----------------
__global__ void k7_softmax_v(const float* __restrict__ logits, float* __restrict__ probs){
  __shared__ float red[1024];
  int b = blockIdx.x, t = threadIdx.x;
  const float* lg = logits + (long)b * V_;
  float* pr = probs + (long)b * V_;
  float m = -1e30f;
  for (int i = t; i < V_; i += 1024) m = fmaxf(m, lg[i]);
  red[t] = m; __syncthreads();
  for (int s = 512; s > 0; s >>= 1){ if (t < s) red[t] = fmaxf(red[t], red[t+s]); __syncthreads(); }
  float M = red[0]; __syncthreads();
  float p = 0.f;
  for (int i = t; i < V_; i += 1024){ float e = __expf(lg[i] - M); pr[i] = e; p += e; }
  red[t] = p; __syncthreads();
  for (int s = 512; s > 0; s >>= 1){ if (t < s) red[t] += red[t+s]; __syncthreads(); }
  float inv = 1.0f / red[0];
  for (int i = t; i < V_; i += 1024) pr[i] *= inv;
}

extern "C" void kernel_launch(void* const* d_in, const int* in_sizes, int n_in,
                              void* d_out, int out_size, void* d_ws, size_t ws_size,
                              hipStream_t stream){
  const float* enc = (const float*)d_in[0];
  const float* dec = (const float*)d_in[1];
  const float* qh  = (const float*)d_in[2];
  const float* W1  = (const float*)d_in[3];
  const float* b1  = (const float*)d_in[4];
  const float* W2  = (const float*)d_in[5];
  const float* b2  = (const float*)d_in[6];
  const float* aV  = (const float*)d_in[7];
  const float* lW  = (const float*)d_in[9];
  const float* lb  = (const float*)d_in[10];
  const float* dW  = (const float*)d_in[11];
  const float* db  = (const float*)d_in[12];

  float* out   = (float*)d_out;
  float* probs = out;                     // 64*50257
  float* hs    = out + 3216448;           // 8*64*1024
  float* cs    = out + 3740736;           // 8*64*1024
  float* attnw = out + 4265024;           // 64*2048

  char* ws = (char*)d_ws;
  unsigned short* W1T = (unsigned short*)(ws + 0);          // 2 MB
  float* score  = (float*)(ws + 2097152);                   // 512 KB
  float* qbias  = (float*)(ws + 2621440);                   // 256 KB
  float* ctx    = (float*)(ws + 2883584);                   // 256 KB
  float* xbuf   = (float*)(ws + 3145728);                   // 256 KB
  float* zpart  = (float*)(ws + 3407872);                   // 6 MB
  float* logits = (float*)(ws + 9699328);                   // 12.9 MB

  hipLaunchKernelGGL(k1a_w1t,      dim3(256),  dim3(256),  0, stream, W1, W1T);
  hipLaunchKernelGGL(k1b_qbias,    dim3(256),  dim3(256),  0, stream, qh, W2, b1, b2, qbias);
  hipLaunchKernelGGL(k2_feat_score,dim3(2048), dim3(K2T),  0, stream, enc, W1T, qbias, aV, score);
  hipLaunchKernelGGL(k3_softmax_s, dim3(64),   dim3(256),  0, stream, score, attnw);
  hipLaunchKernelGGL(k4_ctx,       dim3(512),  dim3(256),  0, stream, enc, attnw, ctx);

  static const int RES[8] = {0,0,1,1,1,1,1,0};
  const float* xin = dec;
  for (int i = 0; i < 8; ++i){
    hipLaunchKernelGGL(k5a_gemm,  dim3(384), dim3(256), 0, stream,
                       xin, ctx, lW + (long)i * 2048 * 4096, zpart);
    hipLaunchKernelGGL(k5b_gates, dim3(64),  dim3(256), 0, stream,
                       zpart, lb + i * 4096, xin, xbuf,
                       hs + i * 65536, cs + i * 65536, RES[i]);
    xin = xbuf;
  }
  hipLaunchKernelGGL(k6_dense,     dim3(786), dim3(256),  0, stream, xbuf, dW, db, logits);
  hipLaunchKernelGGL(k7_softmax_v, dim3(64),  dim3(1024), 0, stream, logits, probs);
}

// Round 4
// 2515.799 us; speedup vs baseline: 1.1521x; 1.1521x over previous
//
#include <hip/hip_runtime.h>
#include <stdint.h>

#define B_  64
#define S_  2048
#define U_  1024
#define V_  50257
#define L_  8

typedef __attribute__((ext_vector_type(4))) float  f32x4;
typedef __attribute__((ext_vector_type(8))) short  bf16x8;
typedef __attribute__((ext_vector_type(4))) unsigned short us4;
typedef __attribute__((ext_vector_type(8))) unsigned short us8;

__device__ inline unsigned short f2bf(float f){
  union { float f; unsigned u; } x; x.f = f;
  unsigned r = (x.u + 0x7FFFu + ((x.u >> 16) & 1u)) >> 16;  // RNE
  return (unsigned short)r;
}
__device__ inline float fast_tanh(float x){
  float e = __expf(2.0f * x);
  return (e - 1.0f) * __builtin_amdgcn_rcpf(e + 1.0f);
}
__device__ inline void gload_lds16(const void* g, void* l){
  __builtin_amdgcn_global_load_lds(
      (const __attribute__((address_space(1))) unsigned int*)g,
      (__attribute__((address_space(3))) unsigned int*)l, 16, 0, 0);
}

// ---------------- K1a: W1 (k,v) fp32 -> W1B tile-major pre-swizzled bf16 ----------------
// W1B[((t*1024 + v)*4 + cp)*8 + e] = bf16(W1[t*32 + (cp ^ ((v>>1)&3))*8 + e][v])
__global__ void k1a_w1b(const float* __restrict__ W1, unsigned short* __restrict__ W1B){
  __shared__ float tile[32][257];
  int tt = blockIdx.x >> 2;             // k-tile 0..31
  int v0 = (blockIdx.x & 3) * 256;
  int t = threadIdx.x;
  #pragma unroll 4
  for (int i = 0; i < 32; ++i){
    int idx = i * 256 + t;
    int r = idx >> 8, c = idx & 255;
    tile[r][c] = W1[(long)(tt * 32 + r) * 1024 + v0 + c];
  }
  __syncthreads();
  #pragma unroll
  for (int i = 0; i < 4; ++i){
    int gid = i * 256 + t;                 // 0..1023
    int vl = gid >> 2, cp = gid & 3;
    int v = v0 + vl;
    int chunk = cp ^ ((v >> 1) & 3);
    us8 o;
    #pragma unroll
    for (int e = 0; e < 8; ++e) o[e] = f2bf(tile[chunk * 8 + e][vl]);
    *(us8*)&W1B[((long)(tt * 1024 + v) * 4 + cp) * 8] = o;
  }
}

// ---------------- K1b: qbias = query_h @ W2 + b2 + b1 ----------------
__global__ void k1b_qbias(const float* __restrict__ qh, const float* __restrict__ W2,
                          const float* __restrict__ b1, const float* __restrict__ b2,
                          float* __restrict__ qbias){
  int b = blockIdx.x >> 2;
  int v = (blockIdx.x & 3) * 256 + threadIdx.x;
  const float* qr = qh + b * 1024;
  float a = 0.f;
  for (int j = 0; j < 256; ++j){
    f32x4 qv = *(const f32x4*)(qr + j * 4);
    a += qv[0] * W2[(long)(j*4+0)*1024 + v] + qv[1] * W2[(long)(j*4+1)*1024 + v]
       + qv[2] * W2[(long)(j*4+2)*1024 + v] + qv[3] * W2[(long)(j*4+3)*1024 + v];
  }
  qbias[b * 1024 + v] = a + b1[v] + b2[v];
}

// ---------------- K2: fused  score = tanh(enc@W1 + qbias) . attn_V ----------------
// Double-buffered 2-phase pipeline (T3 minimum recipe): issue next-tile stage
// BEFORE current-tile compute; one vmcnt-drain barrier per tile.
#define K2T 512
__global__ __launch_bounds__(K2T, 2) void k2_feat_score(
    const float* __restrict__ enc, const unsigned short* __restrict__ W1B,
    const float* __restrict__ qbias, const float* __restrict__ attnV,
    float* __restrict__ score){
  __shared__ __attribute__((aligned(16))) unsigned short Bs[2][1024 * 32]; // 2x64KB
  __shared__ __attribute__((aligned(16))) unsigned short As[2][64 * 40];   // 2x5KB
  __shared__ float scoreL[64];

  const int tid  = threadIdx.x;
  const int lane = tid & 63;
  const int w    = tid >> 6;                 // wave 0..7
  const long row0 = (long)blockIdx.x * 64;
  const int b = blockIdx.x >> 5;

  if (tid < 64) scoreL[tid] = 0.0f;

  f32x4 acc[4][8];
  #pragma unroll
  for (int mi = 0; mi < 4; ++mi)
    #pragma unroll
    for (int ni = 0; ni < 8; ++ni) acc[mi][ni] = (f32x4){0.f,0.f,0.f,0.f};

  const int ar = tid >> 3, ac4 = tid & 7;              // A-stage coords
  const float* aptr = enc + (row0 + ar) * 1024 + ac4 * 4;
  const int aoff = ar * 40 + ac4 * 4;                  // As element offset

  // ---- prologue: tile 0 ----
  #pragma unroll
  for (int i = 0; i < 8; ++i)
    gload_lds16(W1B + (i * 512 + tid) * 8, &Bs[0][(i * 512 + w * 64) * 8]);
  {
    f32x4 av = *(const f32x4*)(aptr);
    us4 sv; sv[0]=f2bf(av[0]); sv[1]=f2bf(av[1]); sv[2]=f2bf(av[2]); sv[3]=f2bf(av[3]);
    *(us4*)&As[0][aoff] = sv;
  }
  __syncthreads();

  int cur = 0;
  for (int t = 0; t < 32; ++t){
    const int nxt = cur ^ 1;
    f32x4 av = (f32x4){0.f,0.f,0.f,0.f};
    if (t < 31){
      const long bbase = (long)(t + 1) * 32768;
      #pragma unroll
      for (int i = 0; i < 8; ++i)
        gload_lds16(W1B + bbase + (i * 512 + tid) * 8, &Bs[nxt][(i * 512 + w * 64) * 8]);
      av = *(const f32x4*)(aptr + (t + 1) * 32);
    }
    // ---- compute tile cur ----
    bf16x8 af[4];
    #pragma unroll
    for (int mi = 0; mi < 4; ++mi){
      int r = mi * 16 + (lane & 15);
      af[mi] = *(const bf16x8*)&As[cur][r * 40 + (lane >> 4) * 8];
    }
    #pragma unroll
    for (int ni = 0; ni < 8; ++ni){
      int v = w * 128 + ni * 16 + (lane & 15);
      int cp = (lane >> 4) ^ ((v >> 1) & 3);
      bf16x8 bf = *(const bf16x8*)&Bs[cur][v * 32 + cp * 8];
      #pragma unroll
      for (int mi = 0; mi < 4; ++mi)
        acc[mi][ni] = __builtin_amdgcn_mfma_f32_16x16x32_bf16(af[mi], bf, acc[mi][ni], 0, 0, 0);
    }
    if (t < 31){
      us4 sv; sv[0]=f2bf(av[0]); sv[1]=f2bf(av[1]); sv[2]=f2bf(av[2]); sv[3]=f2bf(av[3]);
      *(us4*)&As[nxt][aoff] = sv;
    }
    __syncthreads();
    cur = nxt;
  }

  // ---- epilogue: score_row = sum_col tanh(acc + qb[col]) * Vw[col] ----
  float qv[8], vv[8];
  #pragma unroll
  for (int ni = 0; ni < 8; ++ni){
    int col = w * 128 + ni * 16 + (lane & 15);
    qv[ni] = qbias[b * 1024 + col]; vv[ni] = attnV[col];
  }
  #pragma unroll
  for (int mi = 0; mi < 4; ++mi){
    #pragma unroll
    for (int r = 0; r < 4; ++r){
      float t = 0.f;
      #pragma unroll
      for (int ni = 0; ni < 8; ++ni)
        t += fast_tanh(acc[mi][ni][r] + qv[ni]) * vv[ni];
      #pragma unroll
      for (int off = 1; off < 16; off <<= 1) t += __shfl_xor(t, off, 16);
      if ((lane & 15) == 0)
        atomicAdd(&scoreL[mi * 16 + (lane >> 4) * 4 + r], t);
    }
  }
  __syncthreads();
  if (tid < 64) score[row0 + tid] = scoreL[tid];
}

// ---------------- K3: softmax over S per batch ----------------
__global__ void k3_softmax_s(const float* __restrict__ score, float* __restrict__ attnw){
  __shared__ float red[256];
  int b = blockIdx.x, t = threadIdx.x;
  const float* sc = score + b * 2048;
  float m = -1e30f;
  for (int i = t; i < 2048; i += 256) m = fmaxf(m, sc[i]);
  red[t] = m; __syncthreads();
  for (int s = 128; s > 0; s >>= 1){ if (t < s) red[t] = fmaxf(red[t], red[t+s]); __syncthreads(); }
  float M = red[0]; __syncthreads();
  float p = 0.f;
  for (int i = t; i < 2048; i += 256) p += __expf(sc[i] - M);
  red[t] = p; __syncthreads();
  for (int s = 128; s > 0; s >>= 1){ if (t < s) red[t] += red[t+s]; __syncthreads(); }
  float inv = 1.0f / red[0];
  for (int i = t; i < 2048; i += 256) attnw[b * 2048 + i] = __expf(sc[i] - M) * inv;
}

// ---------------- K4a: ctx partials over s-chunks (fully coalesced) ----------------
__global__ void k4a_ctxp(const float* __restrict__ enc, const float* __restrict__ attnw,
                         float* __restrict__ ctxp){
  __shared__ float wL[256];
  int b = blockIdx.x >> 3, sc = blockIdx.x & 7;
  int t = threadIdx.x;
  wL[t] = attnw[b * 2048 + sc * 256 + t];
  __syncthreads();
  const float* base = enc + ((long)b * 2048 + sc * 256) * 1024 + t * 4;
  f32x4 a = (f32x4){0.f,0.f,0.f,0.f};
  #pragma unroll 4
  for (int s = 0; s < 256; ++s)
    a += (*(const f32x4*)(base + (long)s * 1024)) * wL[s];
  *(f32x4*)(ctxp + ((long)(sc * 64 + b)) * 1024 + t * 4) = a;
}

__global__ void k4b_ctx(const float* __restrict__ ctxp, float* __restrict__ ctx){
  int b = blockIdx.x, t = threadIdx.x;
  f32x4 a = (f32x4){0.f,0.f,0.f,0.f};
  #pragma unroll
  for (int sc = 0; sc < 8; ++sc)
    a += *(const f32x4*)(ctxp + ((long)(sc * 64 + b)) * 1024 + t * 4);
  *(f32x4*)(ctx + b * 1024 + t * 4) = a;
}

// ---------------- K5a: z-partials for gates i,g,o (f is dead). split-K=8 ----------------
__global__ void k5a_gemm(const float* __restrict__ x, const float* __restrict__ ctx,
                         const float* __restrict__ W, float* __restrict__ zpart){
  __shared__ float inpL[64 * 256];
  int blk = blockIdx.x;
  int nc = blk % 48, ks = blk / 48;
  int t = threadIdx.x;
  int gc = (nc < 16) ? nc * 64 : (nc < 32 ? 2048 + (nc - 16) * 64 : 3072 + (nc - 32) * 64);
  const float* ib = (ks < 4) ? x : ctx;
  int koff = (ks & 3) * 256;
  #pragma unroll 4
  for (int it = 0; it < 16; ++it){
    int idx = it * 256 + t;
    int r = idx >> 6, c4 = idx & 63;
    *(f32x4*)&inpL[r * 256 + c4 * 4] = *(const f32x4*)(ib + (long)r * 1024 + koff + c4 * 4);
  }
  __syncthreads();
  int b4 = (t & 15) * 4, n4 = (t >> 4) * 4;
  f32x4 a0 = (f32x4){0,0,0,0}, a1 = a0, a2 = a0, a3 = a0;
  const float* Wb = W + (long)(ks * 256) * 4096 + gc + n4;
  #pragma unroll 2
  for (int j = 0; j < 64; ++j){
    f32x4 w0 = *(const f32x4*)(Wb + (long)(j*4+0) * 4096);
    f32x4 w1 = *(const f32x4*)(Wb + (long)(j*4+1) * 4096);
    f32x4 w2 = *(const f32x4*)(Wb + (long)(j*4+2) * 4096);
    f32x4 w3 = *(const f32x4*)(Wb + (long)(j*4+3) * 4096);
    f32x4 x0 = *(const f32x4*)&inpL[(b4+0) * 256 + j * 4];
    f32x4 x1 = *(const f32x4*)&inpL[(b4+1) * 256 + j * 4];
    f32x4 x2 = *(const f32x4*)&inpL[(b4+2) * 256 + j * 4];
    f32x4 x3 = *(const f32x4*)&inpL[(b4+3) * 256 + j * 4];
    a0 += w0*x0[0]; a0 += w1*x0[1]; a0 += w2*x0[2]; a0 += w3*x0[3];
    a1 += w0*x1[0]; a1 += w1*x1[1]; a1 += w2*x1[2]; a1 += w3*x1[3];
    a2 += w0*x2[0]; a2 += w1*x2[1]; a2 += w2*x2[2]; a2 += w3*x2[3];
    a3 += w0*x3[0]; a3 += w1*x3[1]; a3 += w2*x3[2]; a3 += w3*x3[3];
  }
  float* zp = zpart + (long)ks * 64 * 3072 + nc * 64 + n4;
  *(f32x4*)(zp + (long)(b4+0) * 3072) = a0;
  *(f32x4*)(zp + (long)(b4+1) * 3072) = a1;
  *(f32x4*)(zp + (long)(b4+2) * 3072) = a2;
  *(f32x4*)(zp + (long)(b4+3) * 3072) = a3;
}

// ---------------- K5b: reduce split-K, gates, residual ----------------
__global__ void k5b_gates(const float* __restrict__ zpart, const float* __restrict__ lb,
                          const float* __restrict__ xin, float* __restrict__ xout,
                          float* __restrict__ hs, float* __restrict__ cs, int resid){
  int b = blockIdx.x, t = threadIdx.x;
  int n4 = t * 4;
  f32x4 zi = (f32x4){0,0,0,0}, zg = zi, zo = zi;
  #pragma unroll
  for (int ks = 0; ks < 8; ++ks){
    const float* zp = zpart + (long)ks * 64 * 3072 + b * 3072;
    zi += *(const f32x4*)(zp + n4);
    zg += *(const f32x4*)(zp + 1024 + n4);
    zo += *(const f32x4*)(zp + 2048 + n4);
  }
  zi += *(const f32x4*)(lb + n4);
  zg += *(const f32x4*)(lb + 2048 + n4);
  zo += *(const f32x4*)(lb + 3072 + n4);
  f32x4 c, h;
  #pragma unroll
  for (int j = 0; j < 4; ++j){
    float cv = (1.f / (1.f + __expf(-zi[j]))) * tanhf(zg[j]);
    float hv = (1.f / (1.f + __expf(-zo[j]))) * tanhf(cv);
    c[j] = cv; h[j] = hv;
  }
  f32x4 xn = h;
  if (resid) xn += *(const f32x4*)(xin + b * 1024 + n4);
  *(f32x4*)(hs + b * 1024 + n4) = h;
  *(f32x4*)(cs + b * 1024 + n4) = c;
  *(f32x4*)(xout + b * 1024 + n4) = xn;
}

// ---------------- K6: logits = x @ dense_W + db (broadcast-x, coalesced-W) ----------------
__global__ __launch_bounds__(256) void k6_dense(const float* __restrict__ x, const float* __restrict__ dW,
                         const float* __restrict__ db, float* __restrict__ logits){
  int t = threadIdx.x;
  int cl = t & 63, bg = t >> 6;                  // wave-uniform bg
  int col = blockIdx.x * 64 + cl;
  int colc = min(col, V_ - 1);
  float acc[16];
  #pragma unroll
  for (int bi = 0; bi < 16; ++bi) acc[bi] = 0.f;
  const float* xb = x + (long)bg * 16 * 1024;
  for (int k4 = 0; k4 < 256; ++k4){
    f32x4 xv[16];
    #pragma unroll
    for (int bi = 0; bi < 16; ++bi)
      xv[bi] = *(const f32x4*)(xb + (long)bi * 1024 + k4 * 4);   // broadcast loads
    #pragma unroll
    for (int j = 0; j < 4; ++j){
      float wv = dW[((long)k4 * 4 + j) * V_ + colc];              // coalesced
      #pragma unroll
      for (int bi = 0; bi < 16; ++bi)
        acc[bi] += xv[bi][j] * wv;
    }
  }
  if (col < V_){
    float bias = db[colc];
    #pragma unroll
    for (int bi = 0; bi < 16; ++bi)
      logits[(long)(bg * 16 + bi) * V_ + col] = acc[bi] + bias;
  }
}

// ---------------- K7: softmax over V ----------------
__global__ void k7_softmax_v(const float* __restrict__ logits, float* __restrict__ probs){
  __shared__ float red[1024];
  int b = blockIdx.x, t = threadIdx.x;
  const float* lg = logits + (long)b * V_;
  float* pr = probs + (long)b * V_;
  float m = -1e30f;
  for (int i = t; i < V_; i += 1024) m = fmaxf(m, lg[i]);
  red[t] = m; __syncthreads();
  for (int s = 512; s > 0; s >>= 1){ if (t < s) red[t] = fmaxf(red[t], red[t+s]); __syncthreads(); }
  float M = red[0]; __syncthreads();
  float p = 0.f;
  for (int i = t; i < V_; i += 1024){ float e = __expf(lg[i] - M); pr[i] = e; p += e; }
  red[t] = p; __syncthreads();
  for (int s = 512; s > 0; s >>= 1){ if (t < s) red[t] += red[t+s]; __syncthreads(); }
  float inv = 1.0f / red[0];
  for (int i = t; i < V_; i += 1024) pr[i] *= inv;
}

extern "C" void kernel_launch(void* const* d_in, const int* in_sizes, int n_in,
                              void* d_out, int out_size, void* d_ws, size_t ws_size,
                              hipStream_t stream){
  const float* enc = (const float*)d_in[0];
  const float* dec = (const float*)d_in[1];
  const float* qh  = (const float*)d_in[2];
  const float* W1  = (const float*)d_in[3];
  const float* b1  = (const float*)d_in[4];
  const float* W2  = (const float*)d_in[5];
  const float* b2  = (const float*)d_in[6];
  const float* aV  = (const float*)d_in[7];
  const float* lW  = (const float*)d_in[9];
  const float* lb  = (const float*)d_in[10];
  const float* dW  = (const float*)d_in[11];
  const float* db  = (const float*)d_in[12];

  float* out   = (float*)d_out;
  float* probs = out;                     // 64*50257
  float* hs    = out + 3216448;           // 8*64*1024
  float* cs    = out + 3740736;           // 8*64*1024
  float* attnw = out + 4265024;           // 64*2048

  char* ws = (char*)d_ws;
  unsigned short* W1B = (unsigned short*)(ws + 0);          // 2 MB
  float* score  = (float*)(ws + 2097152);                   // 512 KB
  float* qbias  = (float*)(ws + 2621440);                   // 256 KB
  float* ctx    = (float*)(ws + 2883584);                   // 256 KB
  float* xbuf   = (float*)(ws + 3145728);                   // 256 KB
  float* ctxp   = (float*)(ws + 3407872);                   // 2 MB
  float* zpart  = (float*)(ws + 5505024);                   // 6 MB (dead before k6)
  float* logits = (float*)(ws + 5505024);                   // 12.9 MB (overlaps zpart)

  hipLaunchKernelGGL(k1a_w1b,      dim3(128),  dim3(256),  0, stream, W1, W1B);
  hipLaunchKernelGGL(k1b_qbias,    dim3(256),  dim3(256),  0, stream, qh, W2, b1, b2, qbias);
  hipLaunchKernelGGL(k2_feat_score,dim3(2048), dim3(K2T),  0, stream, enc, W1B, qbias, aV, score);
  hipLaunchKernelGGL(k3_softmax_s, dim3(64),   dim3(256),  0, stream, score, attnw);
  hipLaunchKernelGGL(k4a_ctxp,     dim3(512),  dim3(256),  0, stream, enc, attnw, ctxp);
  hipLaunchKernelGGL(k4b_ctx,      dim3(64),   dim3(256),  0, stream, ctxp, ctx);

  static const int RES[8] = {0,0,1,1,1,1,1,0};
  const float* xin = dec;
  for (int i = 0; i < 8; ++i){
    hipLaunchKernelGGL(k5a_gemm,  dim3(384), dim3(256), 0, stream,
                       xin, ctx, lW + (long)i * 2048 * 4096, zpart);
    hipLaunchKernelGGL(k5b_gates, dim3(64),  dim3(256), 0, stream,
                       zpart, lb + i * 4096, xin, xbuf,
                       hs + i * 65536, cs + i * 65536, RES[i]);
    xin = xbuf;
  }
  hipLaunchKernelGGL(k6_dense,     dim3(786), dim3(256),  0, stream, xbuf, dW, db, logits);
  hipLaunchKernelGGL(k7_softmax_v, dim3(64),  dim3(1024), 0, stream, logits, probs);
}